// Round 3
// baseline (278.022 us; speedup 1.0000x reference)
//
#include <hip/hip_runtime.h>

// TemporalMultipyPool3D: x (8,512,16,28,28) f32 -> out (8,512,7,1,1) f32
// All three branches derive from the 4x4x4 grid of window maxes m4[it][jw][kh]
// over windows (4,7,7):
//   out[0]   = max over all 64
//   out[1:3] = quarter-sums of 2x2x2 block-maxes (n=2 windows are exact unions)
//   out[3:7] = sixteenth-sums over (jw,kh)           (n=4 windows directly)
// Verified exact (R1 absmax 0.0). Deterministic: no atomics, private-slot LDS.
//
// R2: coalescing fix. R1's row-per-thread loads had 112 B lane stride (4x
// line-request amplification, 273 us = 0.75 TB/s). Now flat float4 loop:
// lane i loads consecutive 16 B -> 1024 B/instruction. 28 % 4 == 0 so a
// float4 never straddles an H-row; its 4 elements split into <=2 kh bins
// fixed by c = idx % 7. Each thread writes a private (lo,hi) LDS pair.

#define SLICE 12544   // 16*28*28 floats per (b,c)
#define NF4   3136    // float4s per slice
#define ROWS  448     // 16*28 H-rows per slice

__global__ __launch_bounds__(256) void tmpool_kernel(const float* __restrict__ x,
                                                     float* __restrict__ out) {
    // part[(r*7+c)*2 + {0,1}] = (lo-bin max, hi-bin max) of float4 (r,c)
    __shared__ __align__(8) float part[ROWS * 7 * 2];  // 25088 B
    __shared__ float m4[64];                            // window maxes it*16+jw*4+kh

    const int tid = threadIdx.x;
    const int bc  = blockIdx.x;
    const float4* base = (const float4*)(x + (size_t)bc * SLICE);

    // Phase 1: fully-coalesced flat float4 loads (12-13 per thread).
    for (int idx = tid; idx < NF4; idx += 256) {
        const float4 v = base[idx];
        const int r  = idx / 7;        // magic-mul, idx < 3136
        const int c  = idx - r * 7;
        const int h0 = c * 4;
        const int blo = h0 / 7;
        float ml = v.x;                // h0 is always in the lo bin
        float mh = -INFINITY;
        if ((h0 + 1) / 7 == blo) ml = fmaxf(ml, v.y); else mh = fmaxf(mh, v.y);
        if ((h0 + 2) / 7 == blo) ml = fmaxf(ml, v.z); else mh = fmaxf(mh, v.z);
        if ((h0 + 3) / 7 == blo) ml = fmaxf(ml, v.w); else mh = fmaxf(mh, v.w);
        *(float2*)&part[idx * 2] = make_float2(ml, mh);  // ds_write_b64, stride 8 B
    }
    __syncthreads();

    // Phase 2: 64 owner threads, one per (it,jw,kh) window bin.
    // Per row, each kh bin has <=3 contributing (c, lo/hi) slots; offsets are
    // c*2+s within the row's 14-float group, padded with a duplicate:
    //   kh0 <- (c0,lo)(c1,lo)        = {0,2,2}
    //   kh1 <- (c1,hi)(c2,lo)(c3,lo) = {3,4,6}
    //   kh2 <- (c3,hi)(c4,lo)(c5,lo) = {7,8,10}
    //   kh3 <- (c5,hi)(c6,lo)        = {11,12,12}
    if (tid < 64) {
        const int it = tid >> 4, jw = (tid >> 2) & 3, kh = tid & 3;
        const int off0_tab[4] = {0, 3, 7, 11};
        const int off1_tab[4] = {2, 4, 8, 12};
        const int off2_tab[4] = {2, 6, 10, 12};
        const int o0 = off0_tab[kh], o1 = off1_tab[kh], o2 = off2_tab[kh];
        float m = -INFINITY;
        #pragma unroll
        for (int dt = 0; dt < 4; dt++) {
            const int r = (4 * it + dt) * 28 + 7 * jw;
            #pragma unroll
            for (int dw = 0; dw < 7; dw++) {
                const float* p = &part[(r + dw) * 14];
                m = fmaxf(m, fmaxf(fmaxf(p[o0], p[o1]), p[o2]));
            }
        }
        m4[tid] = m;
    }
    __syncthreads();

    // Phase 3: 7 outputs per (b,c).
    if (tid < 7) {
        float* o = out + (size_t)bc * 7;
        if (tid == 0) {
            float m = -INFINITY;
            #pragma unroll
            for (int i = 0; i < 64; i++) m = fmaxf(m, m4[i]);
            o[0] = m;
        } else if (tid < 3) {
            const int i2 = tid - 1;
            float s = 0.f;
            #pragma unroll
            for (int j2 = 0; j2 < 2; j2++)
                #pragma unroll
                for (int k2 = 0; k2 < 2; k2++) {
                    float m = -INFINITY;
                    #pragma unroll
                    for (int di = 0; di < 2; di++)
                        #pragma unroll
                        for (int dj = 0; dj < 2; dj++)
                            #pragma unroll
                            for (int dk = 0; dk < 2; dk++)
                                m = fmaxf(m, m4[(2 * i2 + di) * 16 +
                                                (2 * j2 + dj) * 4 + (2 * k2 + dk)]);
                    s += m;
                }
            o[1 + i2] = s * 0.25f;
        } else {
            const int i = tid - 3;
            float s = 0.f;
            #pragma unroll
            for (int jk = 0; jk < 16; jk++) s += m4[i * 16 + jk];
            o[3 + i] = s * (1.0f / 16.0f);
        }
    }
}

extern "C" void kernel_launch(void* const* d_in, const int* in_sizes, int n_in,
                              void* d_out, int out_size, void* d_ws, size_t ws_size,
                              hipStream_t stream) {
    const float* x = (const float*)d_in[0];
    float* out = (float*)d_out;
    // 8*512 = 4096 (b,c) slices, one block each
    tmpool_kernel<<<4096, 256, 0, stream>>>(x, out);
}

// Round 4
// 276.285 us; speedup vs baseline: 1.0063x; 1.0063x over previous
//
#include <hip/hip_runtime.h>

// TemporalMultipyPool3D: x (8,512,16,28,28) f32 -> out (8,512,7,1,1) f32
// All three branches derive from the 4x4x4 grid of window maxes m4[it][jw][kh]
// over windows (4,7,7):
//   out[0]   = max over all 64
//   out[1:3] = quarter-sums of 2x2x2 block-maxes (n=2 windows are exact unions)
//   out[3:7] = sixteenth-sums over (jw,kh)           (n=4 windows directly)
// Verified exact (R1/R2 absmax 0.0). Deterministic: no atomics anywhere.
//
// R3: phase-2 parallelized 64->256 threads (one (bin,dt) pair per thread,
// quad shfl_xor combine), LDS row-group stride padded 14->15 floats to break
// the sub-lane bank aliasing (stride-14: banks independent of the dt-subthread
// -> 8-way; stride-15: <=3-way). Phase-1 LDS stores are 2x ds_write_b32
// (odd float offsets under stride 15 forbid b64). Phase-1 loads 2-way unrolled.
// Bench floor note: harness resets (822 MB ws fill = 121 us + 205 MB input
// restore) appear to sit inside the timed iteration; kernel itself < 121 us
// (absent from rocprof top-5 in R2).

#define SLICE 12544   // 16*28*28 floats per (b,c)
#define NF4   3136    // float4s per slice
#define ROWS  448     // 16*28 H-rows per slice
#define PSTR  15      // padded floats per row group (14 used + 1 pad)

__device__ __forceinline__ void binmax_store(float* __restrict__ part,
                                             const float4 v, const int idx) {
    const int r  = idx / 7;       // magic-mul, idx < 3136
    const int c  = idx - r * 7;
    const int h0 = c * 4;
    const int blo = h0 / 7;
    float ml = v.x;               // h0 always lands in the lo bin
    float mh = -INFINITY;
    if ((h0 + 1) / 7 == blo) ml = fmaxf(ml, v.y); else mh = fmaxf(mh, v.y);
    if ((h0 + 2) / 7 == blo) ml = fmaxf(ml, v.z); else mh = fmaxf(mh, v.z);
    if ((h0 + 3) / 7 == blo) ml = fmaxf(ml, v.w); else mh = fmaxf(mh, v.w);
    const int s = r * PSTR + c * 2;
    part[s]     = ml;             // two b32 stores: odd offsets under PSTR=15
    part[s + 1] = mh;
}

__global__ __launch_bounds__(256) void tmpool_kernel(const float* __restrict__ x,
                                                     float* __restrict__ out) {
    __shared__ float part[ROWS * PSTR];  // 26880 B: per-float4 (lo,hi) bin maxes
    __shared__ float m4[64];             // window maxes, it*16 + jw*4 + kh

    const int tid = threadIdx.x;
    const int bc  = blockIdx.x;
    const float4* base = (const float4*)(x + (size_t)bc * SLICE);

    // Phase 1: fully-coalesced flat float4 loads, 2-way unrolled (12 + tail).
    #pragma unroll
    for (int i = 0; i < 6; i++) {
        const int idx0 = tid + i * 512;
        const int idx1 = idx0 + 256;
        const float4 a = base[idx0];
        const float4 b = base[idx1];
        binmax_store(part, a, idx0);
        binmax_store(part, b, idx1);
    }
    if (tid < 64) {
        const int idx = 3072 + tid;
        binmax_store(part, base[idx], idx);
    }
    __syncthreads();

    // Phase 2: 256 threads = 64 bins x 4 dt-subthreads. Per row, each kh bin
    // draws from <=3 slots of the row's 14-float group (c*2 + lo/hi), padded
    // with a duplicate:
    //   kh0 <- {0,2,2}   kh1 <- {3,4,6}   kh2 <- {7,8,10}   kh3 <- {11,12,12}
    {
        const int sub = tid & 3;          // = dt
        const int bin = tid >> 2;         // it*16 + jw*4 + kh
        const int it  = bin >> 4, jw = (bin >> 2) & 3, kh = bin & 3;
        const int off0_tab[4] = {0, 3, 7, 11};
        const int off1_tab[4] = {2, 4, 8, 12};
        const int off2_tab[4] = {2, 6, 10, 12};
        const int o0 = off0_tab[kh], o1 = off1_tab[kh], o2 = off2_tab[kh];
        const int rbase = ((4 * it + sub) * 28 + 7 * jw) * PSTR;
        float m = -INFINITY;
        #pragma unroll
        for (int dw = 0; dw < 7; dw++) {
            const float* p = &part[rbase + dw * PSTR];
            m = fmaxf(m, fmaxf(fmaxf(p[o0], p[o1]), p[o2]));
        }
        // combine the 4 dt-partials within each lane quad
        m = fmaxf(m, __shfl_xor(m, 1));
        m = fmaxf(m, __shfl_xor(m, 2));
        if (sub == 0) m4[bin] = m;
    }
    __syncthreads();

    // Phase 3: 7 outputs per (b,c).
    if (tid < 7) {
        float* o = out + (size_t)bc * 7;
        if (tid == 0) {
            float m = -INFINITY;
            #pragma unroll
            for (int i = 0; i < 64; i++) m = fmaxf(m, m4[i]);
            o[0] = m;
        } else if (tid < 3) {
            const int i2 = tid - 1;
            float s = 0.f;
            #pragma unroll
            for (int j2 = 0; j2 < 2; j2++)
                #pragma unroll
                for (int k2 = 0; k2 < 2; k2++) {
                    float m = -INFINITY;
                    #pragma unroll
                    for (int di = 0; di < 2; di++)
                        #pragma unroll
                        for (int dj = 0; dj < 2; dj++)
                            #pragma unroll
                            for (int dk = 0; dk < 2; dk++)
                                m = fmaxf(m, m4[(2 * i2 + di) * 16 +
                                                (2 * j2 + dj) * 4 + (2 * k2 + dk)]);
                    s += m;
                }
            o[1 + i2] = s * 0.25f;
        } else {
            const int i = tid - 3;
            float s = 0.f;
            #pragma unroll
            for (int jk = 0; jk < 16; jk++) s += m4[i * 16 + jk];
            o[3 + i] = s * (1.0f / 16.0f);
        }
    }
}

extern "C" void kernel_launch(void* const* d_in, const int* in_sizes, int n_in,
                              void* d_out, int out_size, void* d_ws, size_t ws_size,
                              hipStream_t stream) {
    const float* x = (const float*)d_in[0];
    float* out = (float*)d_out;
    // 8*512 = 4096 (b,c) slices, one block each
    tmpool_kernel<<<4096, 256, 0, stream>>>(x, out);
}